// Round 5
// baseline (6503.548 us; speedup 1.0000x reference)
//
#include <hip/hip_runtime.h>

// ============================================================================
// 2-layer dynamic-quantized LSTM, T=1024, B=16, I=H=1024.  Round 5.
//
// Key change vs round 4: the recurrence transport is GLOBAL-SCALE INT8 in
// self-validating tagged granules (dwordx2 {4xint8 payload, u32 tag}).
//  - No producer ack-wait, no separate data flag: an 8B store is atomic, so
//    consumers speculatively load granules and check tag == expected step.
//  - Two-phase step: (a) poll pubs {tag, blockmax} -> gmax -> scales,
//    (b) quantize OWN h chunk (512B, from LDS hstash) -> tagged granules +
//    direct LDS stage, (c) spec-load other 31 blocks' granules (16KB int8).
//  - Layer1 consumes the SAME ring0 granules (h0(u), tag u+2) and gets its
//    x-scale from the same pubs0 poll -> h0q/hmax0f paths deleted.
//  - Tags are exact-==; pubs ring 4 slots (slot=tag&3), data ring 8 slots
//    (slot=tag&7). Cross-layer guard: L0 step s polls pubs1[(s-2)&3]==s-2
//    (L1 completed s-4) before overwriting anything L1 still needs.
//    Conventions: end of step s publishes pub tag s+2; h(s-1) granules
//    carry tag s+1 (written early in step s; init pre-stages tag 1).
//
// Workspace:
//   [0,16)        u32 wmax[4]
//   [128,1152)    v2u pubs0[4][32]   [1152,2176) v2u pubs1[4][32]
//   [64K,320K)    i8  ring0[8][32][128] granules (8B each, 32KB/slot)
//   [320K,576K)   i8  ring1[8][...]
//   [1M,17M)      i8  wq[4][4096][1024]
//   [17M,33M)     i8  xq_sw[1024][16][64][16]   (fragment-swizzled)
// ============================================================================

#define T_STEPS 1024

typedef int v4i __attribute__((ext_vector_type(4)));
typedef float v4f __attribute__((ext_vector_type(4)));
typedef unsigned v2u __attribute__((ext_vector_type(2)));

#define DEV static __device__ __forceinline__

DEV float qclip(float v) { return fminf(fmaxf(v, -127.0f), 127.0f); }

DEV unsigned pack4i(float a, float b, float c, float d) {
  int ia = (int)a, ib = (int)b, ic = (int)c, id = (int)d;
  return (unsigned)(ia & 0xff) | ((unsigned)(ib & 0xff) << 8) |
         ((unsigned)(ic & 0xff) << 16) | ((unsigned)(id & 0xff) << 24);
}

DEV float qdiv(float v, float s) { return qclip(rintf(v / s)); }      // one-time
DEV float qmul(float v, float inv) { return qclip(rintf(v * inv)); }  // hot loop

// ---- coherent (LLC) ops: bypass non-coherent per-XCD L1/L2 -----------------
DEV v2u cloadi2(const void* p) {  // no wait; caller drains with vdone()
  v2u r;
  asm volatile("global_load_dwordx2 %0, %1, off sc0 sc1" : "=v"(r) : "v"(p) : "memory");
  return r;
}
DEV v2u cload8w(const void* p) {  // poll load, wait included
  v2u r;
  asm volatile("global_load_dwordx2 %0, %1, off sc0 sc1\n\ts_waitcnt vmcnt(0)"
               : "=v"(r) : "v"(p) : "memory");
  return r;
}
DEV void cstore8(void* p, v2u v) {
  asm volatile("global_store_dwordx2 %0, %1, off sc0 sc1" :: "v"(p), "v"(v) : "memory");
}
DEV void vdone() {  // drain this wave's vmem; fence scheduler (rule 18)
  asm volatile("s_waitcnt vmcnt(0)" ::: "memory");
  __builtin_amdgcn_sched_barrier(0);
}

#define MFMA_I8 __builtin_amdgcn_mfma_i32_16x16x64_i8

// ---------------------------------------------------------------------------
// init: pre-stage h(-1) for both layers: pubs tag 1 (per-chunk maxes) and
// int8 granules tag 1 in data-ring slot 1 (global-scale, exact qdiv).
__global__ void init_kernel(const float* __restrict__ h0in, char* __restrict__ ws) {
  const int layer = blockIdx.x;
  const int tid = threadIdx.x;
  const float* src = h0in + layer * 16384;
  char* ring = ws + 65536 + layer * 262144 + 32768;   // slot 1
  v2u* pubs = (v2u*)(ws + 128 + layer * 1024) + 32;   // slot 1
  __shared__ float red[256];
  __shared__ float chmax[32];
  const int lb = tid >> 3, su = tid & 7;
  float m = 0.f;
  for (int b = su * 2; b < su * 2 + 2; ++b)
    for (int q = 0; q < 32; ++q) m = fmaxf(m, fabsf(src[b * 1024 + lb * 32 + q]));
  red[tid] = m;
  __syncthreads();
  if (su == 0) {
    float mm = red[tid];
#pragma unroll
    for (int i = 1; i < 8; ++i) mm = fmaxf(mm, red[tid + i]);
    chmax[lb] = mm;
    v2u p;
    p.x = 1u;
    p.y = __float_as_uint(mm);
    cstore8((char*)&pubs[lb], p);
  }
  __syncthreads();
  float gm = chmax[0];
  for (int i = 1; i < 32; ++i) gm = fmaxf(gm, chmax[i]);
  const float s = fmaxf(gm, 1e-8f) / 127.0f;
  for (int i = 0; i < 16; ++i) {
    int G = tid + (i << 8);
    int glb = G >> 7, g = G & 127, b = g >> 3, cg = g & 7;
    const float* v = src + b * 1024 + glb * 32 + (cg << 2);
    v2u gr;
    gr.x = pack4i(qdiv(v[0], s), qdiv(v[1], s), qdiv(v[2], s), qdiv(v[3], s));
    gr.y = 1u;
    cstore8(ring + (G << 3), gr);
  }
}

// ---------------------------------------------------------------------------
__global__ void wabsmax_kernel(const float* __restrict__ w0, const float* __restrict__ w1,
                               const float* __restrict__ w2, const float* __restrict__ w3,
                               unsigned* wmax) {
  const int tensor = blockIdx.x >> 8;
  const int blk = blockIdx.x & 255;
  const float* w = tensor == 0 ? w0 : tensor == 1 ? w1 : tensor == 2 ? w2 : w3;
  const int tid = threadIdx.x;
  const float4* src = (const float4*)w;
  float m = 0.0f;
#pragma unroll
  for (int i = 0; i < 16; ++i) {
    float4 v = src[blk * 4096 + (i << 8) + tid];
    m = fmaxf(m, fmaxf(fmaxf(fabsf(v.x), fabsf(v.y)), fmaxf(fabsf(v.z), fabsf(v.w))));
  }
  __shared__ float red[256];
  red[tid] = m;
  __syncthreads();
  for (int off = 128; off > 0; off >>= 1) {
    if (tid < off) red[tid] = fmaxf(red[tid], red[tid + off]);
    __syncthreads();
  }
  if (tid == 0)
    __hip_atomic_fetch_max(&wmax[tensor], __float_as_uint(red[0]),
                           __ATOMIC_RELAXED, __HIP_MEMORY_SCOPE_AGENT);
}

// ---------------------------------------------------------------------------
__global__ void wquant_kernel(const float* __restrict__ w0, const float* __restrict__ w1,
                              const float* __restrict__ w2, const float* __restrict__ w3,
                              const unsigned* __restrict__ wmax,
                              unsigned char* __restrict__ wq) {
  const int tensor = blockIdx.x >> 12;
  const int blk = blockIdx.x & 4095;
  const float* w = tensor == 0 ? w0 : tensor == 1 ? w1 : tensor == 2 ? w2 : w3;
  const float s = fmaxf(__uint_as_float(wmax[tensor]), 1e-8f) / 127.0f;
  const int f4 = (blk << 8) + threadIdx.x;
  float4 v = ((const float4*)w)[f4];
  unsigned* dst = (unsigned*)(wq + (size_t)tensor * 4194304u);
  dst[f4] = pack4i(qdiv(v.x, s), qdiv(v.y, s), qdiv(v.z, s), qdiv(v.w, s));
}

// ---------------------------------------------------------------------------
// xq written SWIZZLED: xq_sw[t][kk][lane][j] = q(x[t][lane&15][kk*64+(lane>>4)*16+j])
__global__ void xquant_kernel(const float* __restrict__ x, float* __restrict__ xscale,
                              unsigned char* __restrict__ xq) {
  const int t = blockIdx.x;
  const int tid = threadIdx.x;
  const float4* src = (const float4*)(x + (size_t)t * 16384u);
  float4 vb[16];
  float m = 0.0f;
#pragma unroll
  for (int i = 0; i < 16; ++i) {
    float4 v = src[(i << 8) + tid];
    vb[i] = v;
    m = fmaxf(m, fmaxf(fmaxf(fabsf(v.x), fabsf(v.y)), fmaxf(fabsf(v.z), fabsf(v.w))));
  }
  __shared__ float red[256];
  red[tid] = m;
  __syncthreads();
  for (int off = 128; off > 0; off >>= 1) {
    if (tid < off) red[tid] = fmaxf(red[tid], red[tid + off]);
    __syncthreads();
  }
  __shared__ float ssh;
  if (tid == 0) {
    float s = fmaxf(red[0], 1e-8f) / 127.0f;
    xscale[t] = s;
    ssh = s;
  }
  __syncthreads();
  const float s = ssh;
  unsigned char* dst = xq + ((size_t)t << 14);
  const int kk = tid >> 4;
  const int hi = (tid >> 2) & 3;
  const int jo = (tid & 3) << 2;
#pragma unroll
  for (int i = 0; i < 16; ++i) {
    float4 v = vb[i];
    unsigned q = pack4i(qdiv(v.x, s), qdiv(v.y, s), qdiv(v.z, s), qdiv(v.w, s));
    *(unsigned*)(dst + (kk << 10) + ((i | (hi << 4)) << 4) + jo) = q;
  }
}

// ---------------------------------------------------------------------------
__global__ __launch_bounds__(512, 2) void seq_kernel(
    const unsigned char* __restrict__ xq, const float* __restrict__ xscale,
    const unsigned char* __restrict__ wq_base, const unsigned* __restrict__ wmax,
    const float* __restrict__ bih0, const float* __restrict__ bhh0,
    const float* __restrict__ bih1, const float* __restrict__ bhh1,
    char* __restrict__ ws, const float* __restrict__ c0in, float* __restrict__ dout) {
  const int blk = blockIdx.x;
  const int layer = blk >> 5;
  const int lb = blk & 31;
  const int j0 = lb << 5;
  const int tid = threadIdx.x;
  const int w = tid >> 6;
  const int lane = tid & 63;
  const int gate = (lane >> 2) & 3;
  const int unit_l = (w << 2) + (lane & 3);
  const int b0 = (lane >> 4) << 2;

  v2u* pubs0 = (v2u*)(ws + 128);
  v2u* pubs1 = (v2u*)(ws + 1152);
  char* ring0 = ws + 65536;
  char* ring1 = ws + 65536 + 262144;

  __shared__ __align__(16) unsigned char ahq[16][1040];
  __shared__ __align__(16) unsigned char axq[16][1040];
  __shared__ float hstash[16][33];
  __shared__ float redw[8];

  const unsigned char* wqi = wq_base + (size_t)(2 * layer) * 4194304u;
  const unsigned char* wqh = wq_base + (size_t)(2 * layer + 1) * 4194304u;
  const float s_wi = fmaxf(__uint_as_float(wmax[2 * layer + 0]), 1e-8f) / 127.0f;
  const float s_wh = fmaxf(__uint_as_float(wmax[2 * layer + 1]), 1e-8f) / 127.0f;

  // MFMA 16x16x64 i8: A row=lane&15, k=(lane>>4)*16+j; D col=lane&15, row=(lane>>4)*4+r
  const int ncol = (gate << 10) + j0 + unit_l;
  const int ksub = (lane >> 4) << 4;
  const int arow = lane & 15;
  const int gbase = lane & ~12;

  v4i wfi[16], wfh[16];
  {
    const unsigned char* pi = wqi + (size_t)ncol * 1024u + ksub;
    const unsigned char* ph = wqh + (size_t)ncol * 1024u + ksub;
#pragma unroll
    for (int kk = 0; kk < 16; ++kk) {
      wfi[kk] = *(const v4i*)(pi + (kk << 6));
      wfh[kk] = *(const v4i*)(ph + (kk << 6));
    }
  }
  const float bsum = (layer ? bih1 : bih0)[ncol] + (layer ? bhh1 : bhh0)[ncol];

  float cr[4];
#pragma unroll
  for (int r = 0; r < 4; ++r) cr[r] = c0in[(layer << 14) + ((b0 + r) << 10) + j0 + unit_l];

  if (layer == 0) {
    // ========================= LAYER 0: s = 0..T ==========================
    for (int s = 0; s <= T_STEPS; ++s) {
      const bool full = (s < T_STEPS);
      v4i ax0 = {0, 0, 0, 0}, ax1 = {0, 0, 0, 0};
      float sxs = 0.f;
      if (full) {  // pre-poll x work: swizzled coalesced loads -> fragments
        sxs = xscale[s];
        const unsigned char* xb = xq + ((size_t)s << 14) + (lane << 4);
        v4i xa[8];
#pragma unroll
        for (int kk = 0; kk < 8; ++kk) xa[kk] = *(const v4i*)(xb + (kk << 10));
#pragma unroll
        for (int kk = 0; kk < 8; kk += 2) {
          ax0 = MFMA_I8(xa[kk], wfi[kk], ax0, 0, 0, 0);
          ax1 = MFMA_I8(xa[kk + 1], wfi[kk + 1], ax1, 0, 0, 0);
        }
#pragma unroll
        for (int kk = 0; kk < 8; ++kk) xa[kk] = *(const v4i*)(xb + ((kk + 8) << 10));
#pragma unroll
        for (int kk = 0; kk < 8; kk += 2) {
          ax0 = MFMA_I8(xa[kk], wfi[kk + 8], ax0, 0, 0, 0);
          ax1 = MFMA_I8(xa[kk + 1], wfi[kk + 9], ax1, 0, 0, 0);
        }
      }
      // ---- poll pubs: lanes<32 scale exchange; lanes>=32 cross-layer guard
      const unsigned ptag = (unsigned)(s + 1);
      int gs = s - 2;
      if (gs < 0) gs = 0;
      const v2u* pp = (lane < 32) ? (pubs0 + (((s + 1) & 3) << 5) + lane)
                                  : (pubs1 + ((gs & 3) << 5) + (lane - 32));
      const unsigned etag = (lane < 32) ? ptag : (unsigned)gs;
      v2u pv;
      unsigned guard = 0;
      for (;;) {
        pv = cload8w(pp);
        if (__ballot(pv.x == etag) == ~0ull) break;
        __builtin_amdgcn_s_sleep(1);
        if (++guard > (1u << 20)) break;
      }
      float pm = (lane < 32) ? __uint_as_float(pv.y) : -1e30f;
#pragma unroll
      for (int m = 1; m < 64; m <<= 1) pm = fmaxf(pm, __shfl_xor(pm, m));
      const float sh = fmaxf(pm, 1e-8f) / 127.0f;  // scale of h0(s-1)
      const float inv = 1.0f / sh;

      const int dslot = (s + 1) & 7;
      char* rb = ring0 + dslot * 32768;
      // ---- quantize OWN chunk (from hstash) -> granules + direct LDS stage
      if (s > 0 && tid < 128) {
        int b = tid >> 3, cg = tid & 7;
        unsigned q = pack4i(qmul(hstash[b][(cg << 2)], inv),
                            qmul(hstash[b][(cg << 2) + 1], inv),
                            qmul(hstash[b][(cg << 2) + 2], inv),
                            qmul(hstash[b][(cg << 2) + 3], inv));
        *(unsigned*)&ahq[b][j0 + (cg << 2)] = q;
        v2u gr;
        gr.x = q;
        gr.y = ptag;
        cstore8(rb + (((lb << 7) + tid) << 3), gr);
      }
      if (full) {
        // ---- spec-load all 32 chunks' granules (own auto-pass when s>0)
        v2u gv[8];
        unsigned guard2 = 0;
        for (;;) {
#pragma unroll
          for (int i = 0; i < 8; ++i) gv[i] = cloadi2(rb + ((tid + (i << 9)) << 3));
          vdone();
          unsigned good = 1u;
#pragma unroll
          for (int i = 0; i < 8; ++i) {
            int G = tid + (i << 9);
            bool own = ((G >> 7) == lb) && (s > 0);
            good &= (own || gv[i].y == ptag) ? 1u : 0u;
          }
          if (__ballot(good != 0u) == ~0ull) break;
          __builtin_amdgcn_s_sleep(1);
          if (++guard2 > (1u << 20)) break;
        }
#pragma unroll
        for (int i = 0; i < 8; ++i) {
          int G = tid + (i << 9);
          int glb = G >> 7, g = G & 127;
          if (!((glb == lb) && (s > 0)))
            *(unsigned*)&ahq[g >> 3][(glb << 5) + ((g & 7) << 2)] = gv[i].x;
        }
        __syncthreads();
        v4i ah0 = {0, 0, 0, 0}, ah1 = {0, 0, 0, 0};
#pragma unroll
        for (int kk = 0; kk < 16; kk += 2) {
          v4i a = *(const v4i*)&ahq[arow][(kk << 6) + ksub];
          v4i b = *(const v4i*)&ahq[arow][((kk + 1) << 6) + ksub];
          ah0 = MFMA_I8(a, wfh[kk], ah0, 0, 0, 0);
          ah1 = MFMA_I8(b, wfh[kk + 1], ah1, 0, 0, 0);
        }
        const float fx = sxs * s_wi, fh = sh * s_wh;
        float am = 0.f;
#pragma unroll
        for (int r = 0; r < 4; ++r) {
          float gv2 = (float)(ax0[r] + ax1[r]) * fx + (float)(ah0[r] + ah1[r]) * fh + bsum;
          float xxv = (gate == 2) ? 2.f * gv2 : gv2;
          float sg = __fdividef(1.f, 1.f + __expf(-xxv));
          float act = (gate == 2) ? 2.f * sg - 1.f : sg;
          float gi = __shfl(act, gbase);
          float gf = __shfl(act, gbase | 4);
          float gg = __shfl(act, gbase | 8);
          float go = __shfl(act, gbase | 12);
          float cn = gf * cr[r] + gi * gg;
          cr[r] = cn;
          float h = go * (2.f * __fdividef(1.f, 1.f + __expf(-2.f * cn)) - 1.f);
          if (gate == 0) hstash[b0 + r][unit_l] = h;
          am = fmaxf(am, fabsf(h));
        }
#pragma unroll
        for (int m = 1; m < 64; m <<= 1) am = fmaxf(am, __shfl_xor(am, m));
        if (lane == 0) redw[w] = am;
        __syncthreads();
        if (tid < 128 && s == T_STEPS - 1) {  // h_n from hstash (plain)
          int b = tid >> 3, c = (tid & 7) << 2;
          v4f hw = {hstash[b][c], hstash[b][c + 1], hstash[b][c + 2], hstash[b][c + 3]};
          *(v4f*)(dout + 16777216u + (b << 10) + j0 + c) = hw;
        }
        if (tid == 0) {  // pub: {tag s+2, blockmax of h0(s)} -- no ack wait!
          float bm = redw[0];
#pragma unroll
          for (int i = 1; i < 8; ++i) bm = fmaxf(bm, redw[i]);
          v2u pub;
          pub.x = (unsigned)(s + 2);
          pub.y = __float_as_uint(bm);
          cstore8((char*)(pubs0 + (((s + 2) & 3) << 5) + lb), pub);
        }
      }
    }
    if (gate == 0) {
#pragma unroll
      for (int r = 0; r < 4; ++r)
        dout[16777216u + 32768u + ((b0 + r) << 10) + j0 + unit_l] = cr[r];
    }
  } else {
    // ========================= LAYER 1: u = 0..T-1 ========================
    for (int u = 0; u < T_STEPS; ++u) {
      const unsigned xtag = (unsigned)(u + 2);  // pubs0/ring0 tag for h0(u)
      const unsigned htag = (unsigned)(u + 1);  // pubs1/ring1 tag for h1(u-1)
      const v2u* pp = (lane < 32) ? (pubs0 + (((u + 2) & 3) << 5) + lane)
                                  : (pubs1 + (((u + 1) & 3) << 5) + (lane - 32));
      const unsigned etag = (lane < 32) ? xtag : htag;
      v2u pv;
      unsigned guard = 0;
      for (;;) {
        pv = cload8w(pp);
        if (__ballot(pv.x == etag) == ~0ull) break;
        __builtin_amdgcn_s_sleep(1);
        if (++guard > (1u << 20)) break;
      }
      float pm = __uint_as_float(pv.y);
#pragma unroll
      for (int m = 1; m < 32; m <<= 1) pm = fmaxf(pm, __shfl_xor(pm, m));
      const float sxs = fmaxf(__shfl(pm, 0), 1e-8f) / 127.0f;   // scale h0(u)
      const float sh = fmaxf(__shfl(pm, 32), 1e-8f) / 127.0f;   // scale h1(u-1)
      const float inv = 1.0f / sh;

      char* rb1 = ring1 + (((u + 1) & 7)) * 32768;
      const char* rb0 = ring0 + (((u + 2) & 7)) * 32768;
      // quantize OWN h1(u-1) chunk -> granules + LDS stage
      if (u > 0 && tid < 128) {
        int b = tid >> 3, cg = tid & 7;
        unsigned q = pack4i(qmul(hstash[b][(cg << 2)], inv),
                            qmul(hstash[b][(cg << 2) + 1], inv),
                            qmul(hstash[b][(cg << 2) + 2], inv),
                            qmul(hstash[b][(cg << 2) + 3], inv));
        *(unsigned*)&ahq[b][j0 + (cg << 2)] = q;
        v2u gr;
        gr.x = q;
        gr.y = htag;
        cstore8(rb1 + (((lb << 7) + tid) << 3), gr);
      }
      // combined spec-load: ring1 (recurrence) + ring0 (x-side)
      v2u gv[16];
      unsigned guard2 = 0;
      for (;;) {
#pragma unroll
        for (int i = 0; i < 8; ++i) gv[i] = cloadi2(rb1 + ((tid + (i << 9)) << 3));
#pragma unroll
        for (int i = 0; i < 8; ++i) gv[8 + i] = cloadi2(rb0 + ((tid + (i << 9)) << 3));
        vdone();
        unsigned good = 1u;
#pragma unroll
        for (int i = 0; i < 8; ++i) {
          int G = tid + (i << 9);
          bool own = ((G >> 7) == lb) && (u > 0);
          good &= (own || gv[i].y == htag) ? 1u : 0u;
          good &= (gv[8 + i].y == xtag) ? 1u : 0u;
        }
        if (__ballot(good != 0u) == ~0ull) break;
        __builtin_amdgcn_s_sleep(1);
        if (++guard2 > (1u << 20)) break;
      }
#pragma unroll
      for (int i = 0; i < 8; ++i) {
        int G = tid + (i << 9);
        int glb = G >> 7, g = G & 127;
        if (!((glb == lb) && (u > 0)))
          *(unsigned*)&ahq[g >> 3][(glb << 5) + ((g & 7) << 2)] = gv[i].x;
        *(unsigned*)&axq[g >> 3][(glb << 5) + ((g & 7) << 2)] = gv[8 + i].x;
      }
      __syncthreads();
      v4i ax0 = {0, 0, 0, 0}, ax1 = {0, 0, 0, 0};
      v4i ah0 = {0, 0, 0, 0}, ah1 = {0, 0, 0, 0};
#pragma unroll
      for (int kk = 0; kk < 16; kk += 2) {
        v4i a0 = *(const v4i*)&axq[arow][(kk << 6) + ksub];
        v4i a1 = *(const v4i*)&axq[arow][((kk + 1) << 6) + ksub];
        v4i b0v = *(const v4i*)&ahq[arow][(kk << 6) + ksub];
        v4i b1v = *(const v4i*)&ahq[arow][((kk + 1) << 6) + ksub];
        ax0 = MFMA_I8(a0, wfi[kk], ax0, 0, 0, 0);
        ax1 = MFMA_I8(a1, wfi[kk + 1], ax1, 0, 0, 0);
        ah0 = MFMA_I8(b0v, wfh[kk], ah0, 0, 0, 0);
        ah1 = MFMA_I8(b1v, wfh[kk + 1], ah1, 0, 0, 0);
      }
      const float fx = sxs * s_wi, fh = sh * s_wh;
      float am = 0.f;
#pragma unroll
      for (int r = 0; r < 4; ++r) {
        float gv2 = (float)(ax0[r] + ax1[r]) * fx + (float)(ah0[r] + ah1[r]) * fh + bsum;
        float xxv = (gate == 2) ? 2.f * gv2 : gv2;
        float sg = __fdividef(1.f, 1.f + __expf(-xxv));
        float act = (gate == 2) ? 2.f * sg - 1.f : sg;
        float gi = __shfl(act, gbase);
        float gf = __shfl(act, gbase | 4);
        float gg = __shfl(act, gbase | 8);
        float go = __shfl(act, gbase | 12);
        float cn = gf * cr[r] + gi * gg;
        cr[r] = cn;
        float h = go * (2.f * __fdividef(1.f, 1.f + __expf(-2.f * cn)) - 1.f);
        if (gate == 0) hstash[b0 + r][unit_l] = h;
        am = fmaxf(am, fabsf(h));
      }
#pragma unroll
      for (int m = 1; m < 64; m <<= 1) am = fmaxf(am, __shfl_xor(am, m));
      if (lane == 0) redw[w] = am;
      __syncthreads();
      if (tid < 128) {  // y output (plain); h_n at u==T-1
        int b = tid >> 3, c = (tid & 7) << 2;
        v4f hw = {hstash[b][c], hstash[b][c + 1], hstash[b][c + 2], hstash[b][c + 3]};
        *(v4f*)(dout + ((size_t)u << 14) + (b << 10) + j0 + c) = hw;
        if (u == T_STEPS - 1)
          *(v4f*)(dout + 16777216u + 16384u + (b << 10) + j0 + c) = hw;
      }
      if (tid == 0) {
        float bm = redw[0];
#pragma unroll
        for (int i = 1; i < 8; ++i) bm = fmaxf(bm, redw[i]);
        v2u pub;
        pub.x = (unsigned)(u + 2);
        pub.y = __float_as_uint(bm);
        cstore8((char*)(pubs1 + (((u + 2) & 3) << 5) + lb), pub);
      }
    }
    if (gate == 0) {
#pragma unroll
      for (int r = 0; r < 4; ++r)
        dout[16777216u + 32768u + 16384u + ((b0 + r) << 10) + j0 + unit_l] = cr[r];
    }
  }
}

// ---------------------------------------------------------------------------
extern "C" void kernel_launch(void* const* d_in, const int* in_sizes, int n_in,
                              void* d_out, int out_size, void* d_ws, size_t ws_size,
                              hipStream_t stream) {
  (void)in_sizes; (void)n_in; (void)out_size; (void)ws_size;
  const float* x     = (const float*)d_in[0];
  const float* h0in  = (const float*)d_in[1];
  const float* c0in  = (const float*)d_in[2];
  const float* w_ih0 = (const float*)d_in[3];
  const float* w_hh0 = (const float*)d_in[4];
  const float* b_ih0 = (const float*)d_in[5];
  const float* b_hh0 = (const float*)d_in[6];
  const float* w_ih1 = (const float*)d_in[7];
  const float* w_hh1 = (const float*)d_in[8];
  const float* b_ih1 = (const float*)d_in[9];
  const float* b_hh1 = (const float*)d_in[10];

  char* ws = (char*)d_ws;
  unsigned* wmax   = (unsigned*)(ws + 0);
  float* xscale    = (float*)(ws + 8192);
  unsigned char* wqb = (unsigned char*)(ws + (1u << 20));
  unsigned char* xq  = (unsigned char*)(ws + (1u << 20) + 4u * 4194304u);

  hipMemsetAsync(ws, 0, 65536, stream);  // wmax, pubs, xscale
  hipLaunchKernelGGL(init_kernel, dim3(2), dim3(256), 0, stream, h0in, ws);
  hipLaunchKernelGGL(wabsmax_kernel, dim3(1024), dim3(256), 0, stream,
                     w_ih0, w_hh0, w_ih1, w_hh1, wmax);
  hipLaunchKernelGGL(wquant_kernel, dim3(16384), dim3(256), 0, stream,
                     w_ih0, w_hh0, w_ih1, w_hh1, wmax, wqb);
  hipLaunchKernelGGL(xquant_kernel, dim3(1024), dim3(256), 0, stream,
                     x, xscale, xq);
  hipLaunchKernelGGL(seq_kernel, dim3(64), dim3(512), 0, stream,
                     xq, xscale, wqb, wmax,
                     b_ih0, b_hh0, b_ih1, b_hh1,
                     ws, c0in, (float*)d_out);
}